// Round 2
// baseline (983.445 us; speedup 1.0000x reference)
//
#include <hip/hip_runtime.h>

// GRU, T=4096, B=256, I=2, H=32, O=1. Only batch row 255 reaches the output.
// Single-wave sequential recurrence; latency/issue-bound.
//
// R5: R4 (DPP tree + permlane32_swap r/z exchange) failed absmax=6.4e-2.
// Analysis: DPP tree and swizzle-partner-recompute verify on paper; the
// permlane32_swap half-direction is the one un-verifiable component (a full
// two-register exchange semantics would silently diverge the wave halves and
// produce exactly this mild error). This version REMOVES the cross-half gate
// exchange: each lane computes r, z, AND n rows for its own h element
// (3 dots instead of 2). Both halves fully redundant, bitwise identical.
// Keeps: LDS-free h replication via DPP xor-butterfly (masks 15,7,2,1);
// cross-16 seed h[low^16] recomputed from partner's (z,n) fetched via
// ds_swizzle xor16 issued one step early (latency spans the loop boundary);
// weights pinned in VGPRs with keep().

#define TT 4096

typedef float v2f __attribute__((ext_vector_type(2)));

__device__ __forceinline__ v2f fma2(v2f a, v2f b, v2f c) {
    return __builtin_elementwise_fma(a, b, c);
}
__device__ __forceinline__ float rl(float v, int l) {
    return __int_as_float(__builtin_amdgcn_readlane(__float_as_int(v), l));
}
__device__ __forceinline__ float fexp2(float x) { return __builtin_amdgcn_exp2f(x); }
__device__ __forceinline__ float frcp(float x)  { return __builtin_amdgcn_rcpf(x); }
__device__ __forceinline__ float keep(float x)  { asm("" : "+v"(x)); return x; }

#define DPP_X1  0xB1   // quad_perm [1,0,3,2] : lane ^= 1
#define DPP_X2  0x4E   // quad_perm [2,3,0,1] : lane ^= 2
#define DPP_X7  0x141  // row_half_mirror     : lane ^= 7
#define DPP_X15 0x140  // row_mirror          : lane ^= 15

template<int CTRL>
__device__ __forceinline__ float dppf(float x) {
    return __int_as_float(__builtin_amdgcn_mov_dpp(__float_as_int(x), CTRL, 0xF, 0xF, false));
}

#define NLOG2E  (-1.44269504088896340736f)   // r/z dots pre-scaled by this
#define TLOG2E  ( 2.88539008177792681472f)   // n dot pre-scaled by this

__global__ __launch_bounds__(64, 1)
__attribute__((amdgpu_waves_per_eu(1, 1)))
void gru_seq(
    const float* __restrict__ x,
    const float* __restrict__ w_ih,
    const float* __restrict__ w_hh,
    const float* __restrict__ b_ih,
    const float* __restrict__ b_hh,
    float* __restrict__ hbuf)
{
    const int lane = threadIdx.x;
    const int low  = lane & 31;
    const int rrow = low;        // r gate row
    const int zrow = 32 + low;   // z gate row
    const int nrow = 64 + low;   // n gate row

    // --- xor-permutation map: tree register i holds h[low ^ sig[i]] ---
    // tree0 (i<16) seeded by h[low]; tree1 (i>=16) seeded by h[low^16].
    // cascade: bit0->^15, bit1->^7, bit2->^2, bit3->^1 (DPP-reachable masks).
    int sig[32];
#pragma unroll
    for (int i2 = 0; i2 < 32; ++i2) {
        int b = i2 & 15;
        int s = (i2 & 16) ? 16 : 0;
        if (b & 1) s ^= 15;
        if (b & 2) s ^= 7;
        if (b & 4) s ^= 2;
        if (b & 8) s ^= 1;
        sig[i2] = s;
    }

    // --- weights, pre-scaled and pre-permuted per lane; pinned in VGPRs ---
    v2f wr[16], wz[16], wn[16];
#pragma unroll
    for (int p = 0; p < 16; ++p) {
        const int c0 = low ^ sig[2 * p], c1 = low ^ sig[2 * p + 1];
        v2f a = { w_hh[rrow * 32 + c0], w_hh[rrow * 32 + c1] };
        v2f b = { w_hh[zrow * 32 + c0], w_hh[zrow * 32 + c1] };
        v2f c = { w_hh[nrow * 32 + c0], w_hh[nrow * 32 + c1] };
        a *= NLOG2E;  b *= NLOG2E;  c *= TLOG2E;
        wr[p].x = keep(a.x); wr[p].y = keep(a.y);
        wz[p].x = keep(b.x); wz[p].y = keep(b.y);
        wn[p].x = keep(c.x); wn[p].y = keep(c.y);
    }
    const float wir0 = keep(w_ih[rrow * 2 + 0] * NLOG2E);
    const float wir1 = keep(w_ih[rrow * 2 + 1] * NLOG2E);
    const float wiz0 = keep(w_ih[zrow * 2 + 0] * NLOG2E);
    const float wiz1 = keep(w_ih[zrow * 2 + 1] * NLOG2E);
    const float win0 = keep(w_ih[nrow * 2 + 0] * TLOG2E);
    const float win1 = keep(w_ih[nrow * 2 + 1] * TLOG2E);
    const float bsr  = keep((b_ih[rrow] + b_hh[rrow]) * NLOG2E);
    const float bsz  = keep((b_ih[zrow] + b_hh[zrow]) * NLOG2E);
    const float bin_ = keep(b_ih[nrow] * TLOG2E);   // outside r*(...)
    const float bhn  = keep(b_hh[nrow] * TLOG2E);   // inside  r*(...)

    float h_el   = 0.0f;   // h[low], identical across wave halves
    float g1prev = 0.0f;   // h[low^16] of previous step
    float zz16   = 0.0f;   // partner's z  (via ds_swizzle xor16, prev step)
    float nv16   = 0.0f;   // partner's n  (via ds_swizzle xor16, prev step)
    float hacc[4];

    // x[t, 255, 0:2] as float2 at index t*256+255; 64 steps per lane-load,
    // prefetched one block ahead.
    const float2* xp = (const float2*)x;
    float2 xv = xp[(size_t)lane * 256 + 255];

    for (int tb = 0; tb < 64; ++tb) {
        float2 xv_next = xv;
        if (tb < 63) xv_next = xp[((size_t)(tb + 1) * 64 + lane) * 256 + 255];
        float4* hout = (float4*)(hbuf + (size_t)low * TT + tb * 64);

#pragma unroll 4
        for (int i = 0; i < 64; ++i) {
            // ---- tree0: replicate own 16-block of h via DPP butterfly ----
            float t0[16];
            t0[0] = h_el;
            t0[1] = dppf<DPP_X15>(t0[0]);
            t0[2] = dppf<DPP_X7>(t0[0]);  t0[3] = dppf<DPP_X7>(t0[1]);
#pragma unroll
            for (int b = 0; b < 4; ++b) t0[4 + b] = dppf<DPP_X2>(t0[b]);
#pragma unroll
            for (int b = 0; b < 8; ++b) t0[8 + b] = dppf<DPP_X1>(t0[b]);

            const float x0 = rl(xv.x, i);
            const float x1 = rl(xv.y, i);
            const float br = fmaf(x1, wir1, fmaf(x0, wir0, bsr));   // scaled
            const float bz = fmaf(x1, wiz1, fmaf(x0, wiz0, bsz));   // scaled
            const float xn = fmaf(x1, win1, fmaf(x0, win0, bin_));  // scaled

            // ---- dots over tree0 while the (prev-step) swizzles land ----
            v2f ar0 = {br,  0.0f}, ar1 = {0.0f, 0.0f};
            v2f az0 = {bz,  0.0f}, az1 = {0.0f, 0.0f};
            v2f an0 = {bhn, 0.0f}, an1 = {0.0f, 0.0f};
#pragma unroll
            for (int p = 0; p < 8; p += 2) {
                v2f ha = {t0[2 * p],     t0[2 * p + 1]};
                v2f hb = {t0[2 * p + 2], t0[2 * p + 3]};
                ar0 = fma2(ha, wr[p],     ar0);
                ar1 = fma2(hb, wr[p + 1], ar1);
                az0 = fma2(ha, wz[p],     az0);
                az1 = fma2(hb, wz[p + 1], az1);
                an0 = fma2(ha, wn[p],     an0);
                an1 = fma2(hb, wn[p + 1], an1);
            }

            // ---- tree1: partner h[low^16] recomputed bitwise-exactly ----
            const float g1 = fmaf(zz16, g1prev - nv16, nv16);
            g1prev = g1;
            float t1[16];
            t1[0] = g1;
            t1[1] = dppf<DPP_X15>(t1[0]);
            t1[2] = dppf<DPP_X7>(t1[0]);  t1[3] = dppf<DPP_X7>(t1[1]);
#pragma unroll
            for (int b = 0; b < 4; ++b) t1[4 + b] = dppf<DPP_X2>(t1[b]);
#pragma unroll
            for (int b = 0; b < 8; ++b) t1[8 + b] = dppf<DPP_X1>(t1[b]);

#pragma unroll
            for (int p = 0; p < 8; p += 2) {
                v2f ha = {t1[2 * p],     t1[2 * p + 1]};
                v2f hb = {t1[2 * p + 2], t1[2 * p + 3]};
                ar0 = fma2(ha, wr[8 + p],     ar0);
                ar1 = fma2(hb, wr[8 + p + 1], ar1);
                az0 = fma2(ha, wz[8 + p],     az0);
                az1 = fma2(hb, wz[8 + p + 1], az1);
                an0 = fma2(ha, wn[8 + p],     an0);
                an1 = fma2(hb, wn[8 + p + 1], an1);
            }

            v2f sr = ar0 + ar1;
            v2f sz = az0 + az1;
            v2f sn = an0 + an1;
            const float pr   = sr.x + sr.y;   // -log2e * (r pre-act)
            const float pz   = sz.x + sz.y;   // -log2e * (z pre-act)
            const float hn_s = sn.x + sn.y;   // 2log2e * (n hidden dot + b_hh)

            const float rr = frcp(1.0f + fexp2(pr));   // sigmoid(r)
            const float zz = frcp(1.0f + fexp2(pz));   // sigmoid(z)
            zz16 = __int_as_float(__builtin_amdgcn_ds_swizzle(__float_as_int(zz), 0x401F));

            // n = tanh(xn + r*hn); arg pre-scaled by 2log2e
            const float nv = fmaf(-2.0f, frcp(1.0f + fexp2(fmaf(rr, hn_s, xn))), 1.0f);
            nv16 = __int_as_float(__builtin_amdgcn_ds_swizzle(__float_as_int(nv), 0x401F));

            h_el = fmaf(zz, h_el - nv, nv);     // h = n + z*(h-n)

            hacc[i & 3] = h_el;
            if ((i & 3) == 3) hout[i >> 2] = *(const float4*)hacc;
        }
        xv = xv_next;
    }
}

// out[t] = sum_j hbuf[j*TT + t] * w_fc[j] + b_fc   (transposed hbuf)
__global__ void fc_out(const float* __restrict__ hbuf,
                       const float* __restrict__ w_fc,
                       const float* __restrict__ b_fc,
                       float* __restrict__ out)
{
    const int t = blockIdx.x * blockDim.x + threadIdx.x;
    if (t >= TT) return;
    float acc = 0.f;
#pragma unroll
    for (int j = 0; j < 32; ++j) acc = fmaf(hbuf[j * TT + t], w_fc[j], acc);
    out[t] = acc + b_fc[0];
}

extern "C" void kernel_launch(void* const* d_in, const int* in_sizes, int n_in,
                              void* d_out, int out_size, void* d_ws, size_t ws_size,
                              hipStream_t stream) {
    const float* x    = (const float*)d_in[0];
    const float* w_ih = (const float*)d_in[1];
    const float* w_hh = (const float*)d_in[2];
    const float* b_ih = (const float*)d_in[3];
    const float* b_hh = (const float*)d_in[4];
    const float* w_fc = (const float*)d_in[5];
    const float* b_fc = (const float*)d_in[6];
    float* out  = (float*)d_out;
    float* hbuf = (float*)d_ws;   // 32*TT*4 = 512 KB

    gru_seq<<<1, 64, 0, stream>>>(x, w_ih, w_hh, b_ih, b_hh, hbuf);
    fc_out<<<TT / 256, 256, 0, stream>>>(hbuf, w_fc, b_fc, out);
}

// Round 4
// 966.982 us; speedup vs baseline: 1.0170x; 1.0170x over previous
//
#include <hip/hip_runtime.h>

// GRU, T=4096, B=256, I=2, H=32, O=1. Only batch row 255 reaches the output.
// Single-wave sequential recurrence; latency/issue-bound.
//
// R7: R5's structure (all-verified primitives, absmax=0) but fix weight
// residency. R5's VGPR_Count=84 < 96 weight regs: the non-volatile keep()
// asm was legally SUNK into the loop together with its feeding load ->
// L1 reload every step (invisible in FETCH_SIZE: w_hh is 12KB, L1-resident)
// ~48 loads/step on an issue-bound single wave = the regression.
// Fix: asm VOLATILE keep() -- volatile asm cannot be sunk into a loop, so
// the weight values are forced live across the loop; at waves_per_eu(1,1)
// the 512-VGPR budget comfortably holds ~160 live regs. Also unroll 4->2 and
// float4->float2 store batching to reduce peak pressure in the unrolled body.
// Permlane*_swap is BANNED (burned R4+R6: probe/use register-coalescing
// inconsistency). Cross-lane ops used are only the bitwise-verified ones:
// DPP 15/7/2/1 butterfly (R5), one-step-early ds_swizzle xor16 (R5).

#define TT 4096

typedef float v2f __attribute__((ext_vector_type(2)));

__device__ __forceinline__ v2f fma2(v2f a, v2f b, v2f c) {
    return __builtin_elementwise_fma(a, b, c);
}
__device__ __forceinline__ float rl(float v, int l) {
    return __int_as_float(__builtin_amdgcn_readlane(__float_as_int(v), l));
}
__device__ __forceinline__ float fexp2(float x) { return __builtin_amdgcn_exp2f(x); }
__device__ __forceinline__ float frcp(float x)  { return __builtin_amdgcn_rcpf(x); }
// volatile: may not be deleted, duplicated, or sunk into the loop.
__device__ __forceinline__ float pin(float x)   { asm volatile("" : "+v"(x)); return x; }

#define DPP_X1  0xB1   // quad_perm [1,0,3,2] : lane ^= 1
#define DPP_X2  0x4E   // quad_perm [2,3,0,1] : lane ^= 2
#define DPP_X7  0x141  // row_half_mirror     : lane ^= 7
#define DPP_X15 0x140  // row_mirror          : lane ^= 15

template<int CTRL>
__device__ __forceinline__ float dppf(float x) {
    return __int_as_float(__builtin_amdgcn_mov_dpp(__float_as_int(x), CTRL, 0xF, 0xF, false));
}

#define NLOG2E  (-1.44269504088896340736f)   // r/z dots pre-scaled by this
#define TLOG2E  ( 2.88539008177792681472f)   // n dot pre-scaled by this

__global__ __launch_bounds__(64, 1)
__attribute__((amdgpu_waves_per_eu(1, 1)))
void gru_seq(
    const float* __restrict__ x,
    const float* __restrict__ w_ih,
    const float* __restrict__ w_hh,
    const float* __restrict__ b_ih,
    const float* __restrict__ b_hh,
    float* __restrict__ hbuf)
{
    const int lane = threadIdx.x;
    const int low  = lane & 31;
    const int rrow = low;        // r gate row
    const int zrow = 32 + low;   // z gate row
    const int nrow = 64 + low;   // n gate row

    // --- xor-permutation map: tree register i holds h[low ^ sig[i]] ---
    // tree0 (i<16) seeded by h[low]; tree1 (i>=16) seeded by h[low^16].
    // cascade: bit0->^15, bit1->^7, bit2->^2, bit3->^1 (DPP-reachable masks).
    int sig[32];
#pragma unroll
    for (int i2 = 0; i2 < 32; ++i2) {
        int b = i2 & 15;
        int s = (i2 & 16) ? 16 : 0;
        if (b & 1) s ^= 15;
        if (b & 2) s ^= 7;
        if (b & 4) s ^= 2;
        if (b & 8) s ^= 1;
        sig[i2] = s;
    }

    // --- weights, pre-scaled and pre-permuted per lane; PINNED in VGPRs ---
    v2f wr[16], wz[16], wn[16];
#pragma unroll
    for (int p = 0; p < 16; ++p) {
        const int c0 = low ^ sig[2 * p], c1 = low ^ sig[2 * p + 1];
        v2f a = { w_hh[rrow * 32 + c0], w_hh[rrow * 32 + c1] };
        v2f b = { w_hh[zrow * 32 + c0], w_hh[zrow * 32 + c1] };
        v2f c = { w_hh[nrow * 32 + c0], w_hh[nrow * 32 + c1] };
        a *= NLOG2E;  b *= NLOG2E;  c *= TLOG2E;
        wr[p].x = pin(a.x); wr[p].y = pin(a.y);
        wz[p].x = pin(b.x); wz[p].y = pin(b.y);
        wn[p].x = pin(c.x); wn[p].y = pin(c.y);
    }
    const float wir0 = pin(w_ih[rrow * 2 + 0] * NLOG2E);
    const float wir1 = pin(w_ih[rrow * 2 + 1] * NLOG2E);
    const float wiz0 = pin(w_ih[zrow * 2 + 0] * NLOG2E);
    const float wiz1 = pin(w_ih[zrow * 2 + 1] * NLOG2E);
    const float win0 = pin(w_ih[nrow * 2 + 0] * TLOG2E);
    const float win1 = pin(w_ih[nrow * 2 + 1] * TLOG2E);
    const float bsr  = pin((b_ih[rrow] + b_hh[rrow]) * NLOG2E);
    const float bsz  = pin((b_ih[zrow] + b_hh[zrow]) * NLOG2E);
    const float bin_ = pin(b_ih[nrow] * TLOG2E);   // outside r*(...)
    const float bhn  = pin(b_hh[nrow] * TLOG2E);   // inside  r*(...)

    float h_el   = 0.0f;   // h[low], identical across wave halves
    float g1prev = 0.0f;   // h[low^16] of previous step
    float zz16   = 0.0f;   // partner's z  (via ds_swizzle xor16, prev step)
    float nv16   = 0.0f;   // partner's n  (via ds_swizzle xor16, prev step)
    float hacc[2];         // 2-step store batch (float2)

    // x[t, 255, 0:2] as float2 at index t*256+255; 64 steps per lane-load,
    // prefetched one block ahead.
    const float2* xp = (const float2*)x;
    float2 xv = xp[(size_t)lane * 256 + 255];

    for (int tb = 0; tb < 64; ++tb) {
        float2 xv_next = xv;
        if (tb < 63) xv_next = xp[((size_t)(tb + 1) * 64 + lane) * 256 + 255];
        float2* hout = (float2*)(hbuf + (size_t)low * TT + tb * 64);

#pragma unroll 2
        for (int i = 0; i < 64; ++i) {
            // ---- tree0: replicate own 16-block of h via DPP butterfly ----
            float t0[16];
            t0[0] = h_el;
            t0[1] = dppf<DPP_X15>(t0[0]);
            t0[2] = dppf<DPP_X7>(t0[0]);  t0[3] = dppf<DPP_X7>(t0[1]);
#pragma unroll
            for (int b = 0; b < 4; ++b) t0[4 + b] = dppf<DPP_X2>(t0[b]);
#pragma unroll
            for (int b = 0; b < 8; ++b) t0[8 + b] = dppf<DPP_X1>(t0[b]);

            const float x0 = rl(xv.x, i);
            const float x1 = rl(xv.y, i);
            const float br = fmaf(x1, wir1, fmaf(x0, wir0, bsr));   // scaled
            const float bz = fmaf(x1, wiz1, fmaf(x0, wiz0, bsz));   // scaled
            const float xn = fmaf(x1, win1, fmaf(x0, win0, bin_));  // scaled

            // ---- dots over tree0 while the (prev-step) swizzles land ----
            v2f ar0 = {br,  0.0f}, ar1 = {0.0f, 0.0f};
            v2f az0 = {bz,  0.0f}, az1 = {0.0f, 0.0f};
            v2f an0 = {bhn, 0.0f}, an1 = {0.0f, 0.0f};
#pragma unroll
            for (int p = 0; p < 8; p += 2) {
                v2f ha = {t0[2 * p],     t0[2 * p + 1]};
                v2f hb = {t0[2 * p + 2], t0[2 * p + 3]};
                ar0 = fma2(ha, wr[p],     ar0);
                ar1 = fma2(hb, wr[p + 1], ar1);
                az0 = fma2(ha, wz[p],     az0);
                az1 = fma2(hb, wz[p + 1], az1);
                an0 = fma2(ha, wn[p],     an0);
                an1 = fma2(hb, wn[p + 1], an1);
            }

            // ---- tree1: partner h[low^16] recomputed bitwise-exactly ----
            const float g1 = fmaf(zz16, g1prev - nv16, nv16);
            g1prev = g1;
            float t1[16];
            t1[0] = g1;
            t1[1] = dppf<DPP_X15>(t1[0]);
            t1[2] = dppf<DPP_X7>(t1[0]);  t1[3] = dppf<DPP_X7>(t1[1]);
#pragma unroll
            for (int b = 0; b < 4; ++b) t1[4 + b] = dppf<DPP_X2>(t1[b]);
#pragma unroll
            for (int b = 0; b < 8; ++b) t1[8 + b] = dppf<DPP_X1>(t1[b]);

#pragma unroll
            for (int p = 0; p < 8; p += 2) {
                v2f ha = {t1[2 * p],     t1[2 * p + 1]};
                v2f hb = {t1[2 * p + 2], t1[2 * p + 3]};
                ar0 = fma2(ha, wr[8 + p],     ar0);
                ar1 = fma2(hb, wr[8 + p + 1], ar1);
                az0 = fma2(ha, wz[8 + p],     az0);
                az1 = fma2(hb, wz[8 + p + 1], az1);
                an0 = fma2(ha, wn[8 + p],     an0);
                an1 = fma2(hb, wn[8 + p + 1], an1);
            }

            v2f sr = ar0 + ar1;
            v2f sz = az0 + az1;
            v2f sn = an0 + an1;
            const float pr   = sr.x + sr.y;   // -log2e * (r pre-act)
            const float pz   = sz.x + sz.y;   // -log2e * (z pre-act)
            const float hn_s = sn.x + sn.y;   // 2log2e * (n hidden dot + b_hh)

            const float rr = frcp(1.0f + fexp2(pr));   // sigmoid(r)
            const float zz = frcp(1.0f + fexp2(pz));   // sigmoid(z)
            zz16 = __int_as_float(__builtin_amdgcn_ds_swizzle(__float_as_int(zz), 0x401F));

            // n = tanh(xn + r*hn); arg pre-scaled by 2log2e
            const float nv = fmaf(-2.0f, frcp(1.0f + fexp2(fmaf(rr, hn_s, xn))), 1.0f);
            nv16 = __int_as_float(__builtin_amdgcn_ds_swizzle(__float_as_int(nv), 0x401F));

            h_el = fmaf(zz, h_el - nv, nv);     // h = n + z*(h-n)

            hacc[i & 1] = h_el;
            if ((i & 1) == 1) hout[i >> 1] = *(const float2*)hacc;
        }
        xv = xv_next;
    }
}

// out[t] = sum_j hbuf[j*TT + t] * w_fc[j] + b_fc   (transposed hbuf)
__global__ void fc_out(const float* __restrict__ hbuf,
                       const float* __restrict__ w_fc,
                       const float* __restrict__ b_fc,
                       float* __restrict__ out)
{
    const int t = blockIdx.x * blockDim.x + threadIdx.x;
    if (t >= TT) return;
    float acc = 0.f;
#pragma unroll
    for (int j = 0; j < 32; ++j) acc = fmaf(hbuf[j * TT + t], w_fc[j], acc);
    out[t] = acc + b_fc[0];
}

extern "C" void kernel_launch(void* const* d_in, const int* in_sizes, int n_in,
                              void* d_out, int out_size, void* d_ws, size_t ws_size,
                              hipStream_t stream) {
    const float* x    = (const float*)d_in[0];
    const float* w_ih = (const float*)d_in[1];
    const float* w_hh = (const float*)d_in[2];
    const float* b_ih = (const float*)d_in[3];
    const float* b_hh = (const float*)d_in[4];
    const float* w_fc = (const float*)d_in[5];
    const float* b_fc = (const float*)d_in[6];
    float* out  = (float*)d_out;
    float* hbuf = (float*)d_ws;   // 32*TT*4 = 512 KB

    gru_seq<<<1, 64, 0, stream>>>(x, w_ih, w_hh, b_ih, b_hh, hbuf);
    fc_out<<<TT / 256, 256, 0, stream>>>(hbuf, w_fc, b_fc, out);
}